// Round 16
// baseline (126.766 us; speedup 1.0000x reference)
//
#include <hip/hip_runtime.h>
#include <cstdint>
#include <cstddef>

typedef unsigned short u16;
typedef unsigned int u32;
typedef __bf16 bf16x8 __attribute__((ext_vector_type(8)));
typedef float f32x4 __attribute__((ext_vector_type(4)));
typedef float f32x16 __attribute__((ext_vector_type(16)));
typedef u32 u32x2 __attribute__((ext_vector_type(2)));
typedef u32 u32x4 __attribute__((ext_vector_type(4)));

#define AS1 __attribute__((address_space(1)))
#define AS3 __attribute__((address_space(3)))

__device__ __forceinline__ void gld16(const u16* g, u16* l) {
  __builtin_amdgcn_global_load_lds((const AS1 void*)(const void*)g,
                                   (AS3 void*)(void*)l, 16, 0, 0);
}

__device__ __forceinline__ u16 f2bf(float f) {
  union { float f; unsigned u; } x; x.f = f;
  return (u16)((x.u + 0x7fffu + ((x.u >> 16) & 1u)) >> 16);
}

// single-instruction exp2 (avoids any OCML call expansion; inputs bounded ~|14|)
__device__ __forceinline__ float fexp2(float x) {
  float r; asm("v_exp_f32 %0, %1" : "=v"(r) : "v"(x)); return r;
}

__device__ __forceinline__ f32x16 zf16() {
  f32x16 v;
#pragma unroll
  for (int i = 0; i < 16; ++i) v[i] = 0.f;
  return v;
}

__device__ __forceinline__ bf16x8 mk8(u32x2 a, u32x2 b) {
  union { u32x4 u; bf16x8 v; } x;
  x.u[0] = a[0]; x.u[1] = a[1]; x.u[2] = b[0]; x.u[3] = b[1];
  return x.v;
}

// ---------- fused prep: z<4 transpose weights fp32->bf16; z==4 convert X ----------
__global__ void k_prep(const float* __restrict__ X,
                       const float* __restrict__ wq, const float* __restrict__ wk,
                       const float* __restrict__ wv, const float* __restrict__ wo,
                       u16* __restrict__ Xb, u16* __restrict__ Wqkv, u16* __restrict__ Wot) {
  const int z = blockIdx.z;
  if (z == 4) {
    int bid = blockIdx.y * 32 + blockIdx.x;
    int tid = threadIdx.y * 32 + threadIdx.x;
#pragma unroll
    for (int k = 0; k < 4; ++k) {
      int i = bid * 1024 + k * 256 + tid;
      float4 v = reinterpret_cast<const float4*>(X)[i];
      ushort4 o;
      o.x = f2bf(v.x); o.y = f2bf(v.y); o.z = f2bf(v.z); o.w = f2bf(v.w);
      reinterpret_cast<ushort4*>(Xb)[i] = o;
    }
    return;
  }
  __shared__ float t[32][33];
  const float* in = (z == 0) ? wq : (z == 1) ? wk : (z == 2) ? wv : wo;
  u16* out = (z < 3) ? (Wqkv + (size_t)z * 1048576) : Wot;
  int bx = blockIdx.x * 32, by = blockIdx.y * 32;
  int tx = threadIdx.x, ty = threadIdx.y;  // (32, 8)
#pragma unroll
  for (int j = 0; j < 32; j += 8)
    t[ty + j][tx] = in[(size_t)(by + ty + j) * 1024 + bx + tx];
  __syncthreads();
#pragma unroll
  for (int j = 0; j < 32; j += 8)
    out[(size_t)(bx + ty + j) * 1024 + by + tx] = f2bf(t[tx][ty + j]);
}

// ---------- GEMM1: [4096 x 3072 x 1024], epilogue scatters Q(scaled)/K/V^T ----------
// Q pre-scaled by DIM_HEAD^-0.5 * log2(e) so attention softmax runs in exp2 domain.
// V-blocks (bn >= 2048, block-uniform) compute the TRANSPOSED tile by swapping
// MFMA operands (A/B fragments share the same lane->row convention, so
// mfma(B,A) yields D^T) -> V^T stores become 32B-contiguous like Q/K.
__global__ __launch_bounds__(256) void k_gemm_qkv(
    const u16* __restrict__ Xb,   // [4096][1024] bf16
    const u16* __restrict__ Wt,   // [3072][1024] bf16 (W^T, q|k|v stacked)
    u16* __restrict__ Qb,         // [B*H][2048][64], pre-scaled
    u16* __restrict__ Kb,         // [B*H][2048][64]
    u16* __restrict__ Vt) {       // [B*H][64][2048]
  __shared__ __align__(16) u16 As[128][32];
  __shared__ __align__(16) u16 Bs[128][32];
  const int tid = threadIdx.x;
  const int w = tid >> 6, l = tid & 63;
  const int bm = blockIdx.x * 128;
  const int bn = blockIdx.y * 128;
  const bool isV = (bn >= 2048);
  const int wm = (w >> 1) * 64, wn = (w & 1) * 64;
  const int lm = l & 15, lg = l >> 4;

  f32x4 acc[4][4];
#pragma unroll
  for (int i = 0; i < 4; ++i)
#pragma unroll
    for (int j = 0; j < 4; ++j) acc[i][j] = f32x4{0.f, 0.f, 0.f, 0.f};

  const int srow = w * 16 + (l >> 2);   // 4 lanes/row, 16 rows per wave-issue
  const int scol = (l & 3) * 8;
  for (int k0 = 0; k0 < 1024; k0 += 32) {
#pragma unroll
    for (int j = 0; j < 2; ++j) {
      gld16(Xb + (size_t)(bm + j * 64 + srow) * 1024 + k0 + scol, &As[j * 64 + w * 16][0]);
      gld16(Wt + (size_t)(bn + j * 64 + srow) * 1024 + k0 + scol, &Bs[j * 64 + w * 16][0]);
    }
    __syncthreads();
    bf16x8 af[4], bfr[4];
#pragma unroll
    for (int mt = 0; mt < 4; ++mt)
      af[mt] = *reinterpret_cast<const bf16x8*>(&As[wm + mt * 16 + lm][lg * 8]);
#pragma unroll
    for (int nt = 0; nt < 4; ++nt)
      bfr[nt] = *reinterpret_cast<const bf16x8*>(&Bs[wn + nt * 16 + lm][lg * 8]);
    if (!isV) {
#pragma unroll
      for (int mt = 0; mt < 4; ++mt)
#pragma unroll
        for (int nt = 0; nt < 4; ++nt)
          acc[mt][nt] = __builtin_amdgcn_mfma_f32_16x16x32_bf16(af[mt], bfr[nt], acc[mt][nt], 0, 0, 0);
    } else {
      // transposed tile: D(i=W-row, j=X-row)
#pragma unroll
      for (int mt = 0; mt < 4; ++mt)
#pragma unroll
        for (int nt = 0; nt < 4; ++nt)
          acc[mt][nt] = __builtin_amdgcn_mfma_f32_16x16x32_bf16(bfr[nt], af[mt], acc[mt][nt], 0, 0, 0);
    }
    __syncthreads();
  }

  if (!isV) {
    // epilogue Q/K: C/D layout col=lane&15 -> gc, row=(lane>>4)*4+reg -> gr
#pragma unroll
    for (int nt = 0; nt < 4; ++nt) {
      int gc = bn + wn + nt * 16 + lm;
      int which = gc >> 10, jc = gc & 1023, h = jc >> 6, d = jc & 63;
#pragma unroll
      for (int mt = 0; mt < 4; ++mt) {
#pragma unroll
        for (int r = 0; r < 4; ++r) {
          int gr = bm + wm + mt * 16 + lg * 4 + r;
          int b = gr >> 11, s = gr & 2047;
          float v = acc[mt][nt][r];
          size_t bh = (size_t)(b * 16 + h);
          if (which == 0) Qb[(bh * 2048 + s) * 64 + d] = f2bf(v * 0.18033688f);
          else            Kb[(bh * 2048 + s) * 64 + d] = f2bf(v);
        }
      }
    }
  } else {
    // epilogue V (transposed tile): row-dim -> gc (W col), col-dim -> gr (X row)
    // s = gr varies with lm -> 16 consecutive u16 per 16-lane group (32B runs)
#pragma unroll
    for (int nt = 0; nt < 4; ++nt) {
#pragma unroll
      for (int r = 0; r < 4; ++r) {
        int gc = bn + wn + nt * 16 + lg * 4 + r;
        int jc = gc & 1023, h = jc >> 6, d = jc & 63;
#pragma unroll
        for (int mt = 0; mt < 4; ++mt) {
          int gr = bm + wm + mt * 16 + lm;
          int b = gr >> 11, s = gr & 2047;
          Vt[((size_t)(b * 16 + h) * 64 + d) * 2048 + s] = f2bf(acc[mt][nt][r]);
        }
      }
    }
  }
}

// ---------- flash attention, swapped-QK^T 32x32, m=0 softmax (R11 verified) ----------
// Per-subtile QK^T+softmax (one f32x16 st live), 16 MFMA/tile, VALU row-sums,
// padded LDS groups (1056B stride), v_exp_f32. 512 blocks, 80 VGPR.
__global__ __launch_bounds__(256) void k_attn(
    const u16* __restrict__ Qb, const u16* __restrict__ Kb,
    const u16* __restrict__ Vt, u16* __restrict__ Ab) {  // Ab: [4096][1024] bf16
  __shared__ __align__(16) u16 Ks[2][4224];   // 2 x 8448B padded K tiles
  __shared__ __align__(16) u16 Vs[2][4224];   // 2 x 8448B padded V tiles [d][kv]
  __shared__ float lb[4][32];
  const int tid = threadIdx.x, w = tid >> 6, l = tid & 63;
  const int lm = l & 31, hi = l >> 5;
  const int kx = lm & 7;
  const int bh = blockIdx.x;
  const int q0 = blockIdx.y * 128 + w * 32;
  const u16* Qh = Qb + (size_t)bh * 2048 * 64;
  const u16* Kh = Kb + (size_t)bh * 2048 * 64;
  const u16* Vh = Vt + (size_t)bh * 64 * 2048;

  // Q fragments (held whole kernel): q = q0+lm, slot (c,hi,i) -> d = 16c+8hi+i
  bf16x8 qf[4];
#pragma unroll
  for (int c = 0; c < 4; ++c)
    qf[c] = *reinterpret_cast<const bf16x8*>(&Qh[(size_t)(q0 + lm) * 64 + 16 * c + 8 * hi]);

  f32x16 o0 = zf16(), o1 = zf16();
  float lsum = 0.f;

  const int sr8 = l >> 3;    // staging row within its 8-row group
  const int sg = l & 7;      // staging phys granule
  // padded row offset for row lm (and +2112 for row 32+lm)
  const int koff = (lm >> 3) * 528 + (lm & 7) * 64;

#define STAGE(tile, buf)                                                          \
  {                                                                               \
    const int kvn_ = (tile) * 64;                                                 \
    _Pragma("unroll")                                                             \
    for (int j = 0; j < 2; ++j) {                                                 \
      int row_ = w * 16 + j * 8 + sr8;                                            \
      int g_ = sg ^ sr8;                                                          \
      gld16(Kh + (size_t)(kvn_ + row_) * 64 + 8 * g_, &Ks[buf][(w * 2 + j) * 528]); \
      gld16(Vh + (size_t)row_ * 2048 + kvn_ + 8 * g_, &Vs[buf][(w * 2 + j) * 528]); \
    }                                                                             \
  }

  // ---- prologue: stage tile 0 into buf 0
  STAGE(0, 0);
  __syncthreads();

  for (int t = 0; t < 32; ++t) {
    const int cur = t & 1, nxt = cur ^ 1;

    // ---- issue next tile's K,V DMA (completes at the end-of-tile barrier)
    if (t < 31) STAGE(t + 1, nxt);

    const u16* Kc = &Ks[cur][0];
    bf16x8 pf[2][2];
    float ps0 = 0.f, ps1 = 0.f, ps2 = 0.f, ps3 = 0.f;

    // ---- subtile 0: S^T rows lm (kv 0..31 of tile), then its softmax
    {
      f32x16 st = zf16();
      __builtin_amdgcn_s_setprio(1);
#pragma unroll
      for (int c = 0; c < 4; ++c) {
        bf16x8 kf = *reinterpret_cast<const bf16x8*>(Kc + koff + 8 * ((2 * c + hi) ^ kx));
        st = __builtin_amdgcn_mfma_f32_32x32x16_bf16(kf, qf[c], st, 0, 0, 0);
      }
      __builtin_amdgcn_s_setprio(0);
#pragma unroll
      for (int j = 0; j < 2; ++j)
#pragma unroll
        for (int ii = 0; ii < 8; ++ii) {
          float p = fexp2(st[8 * j + ii]);
          pf[0][j][ii] = (__bf16)p;
          if ((ii & 3) == 0)      ps0 += p;
          else if ((ii & 3) == 1) ps1 += p;
          else if ((ii & 3) == 2) ps2 += p;
          else                    ps3 += p;
        }
    }
    // ---- subtile 1: S^T rows 32+lm (kv 32..63 of tile), then its softmax
    {
      f32x16 st = zf16();
      __builtin_amdgcn_s_setprio(1);
#pragma unroll
      for (int c = 0; c < 4; ++c) {
        bf16x8 kf = *reinterpret_cast<const bf16x8*>(Kc + koff + 2112 + 8 * ((2 * c + hi) ^ kx));
        st = __builtin_amdgcn_mfma_f32_32x32x16_bf16(kf, qf[c], st, 0, 0, 0);
      }
      __builtin_amdgcn_s_setprio(0);
#pragma unroll
      for (int j = 0; j < 2; ++j)
#pragma unroll
        for (int ii = 0; ii < 8; ++ii) {
          float p = fexp2(st[8 * j + ii]);
          pf[1][j][ii] = (__bf16)p;
          if ((ii & 3) == 0)      ps0 += p;
          else if ((ii & 3) == 1) ps1 += p;
          else if ((ii & 3) == 2) ps2 += p;
          else                    ps3 += p;
        }
    }
    float ps = (ps0 + ps1) + (ps2 + ps3);
    ps += __shfl_xor(ps, 32);
    lsum += ps;

    // ---- O += P V
    const u16* Vc = &Vs[cur][0];
    __builtin_amdgcn_s_setprio(1);
#pragma unroll
    for (int tt = 0; tt < 2; ++tt)
#pragma unroll
      for (int j = 0; j < 2; ++j) {
        int Ga = 4 * tt + 2 * j;
        u32x2 a0 = *reinterpret_cast<const u32x2*>(Vc + koff + 8 * (Ga ^ kx) + 4 * hi);
        u32x2 a1 = *reinterpret_cast<const u32x2*>(Vc + koff + 8 * ((Ga + 1) ^ kx) + 4 * hi);
        u32x2 b0 = *reinterpret_cast<const u32x2*>(Vc + koff + 2112 + 8 * (Ga ^ kx) + 4 * hi);
        u32x2 b1 = *reinterpret_cast<const u32x2*>(Vc + koff + 2112 + 8 * ((Ga + 1) ^ kx) + 4 * hi);
        o0 = __builtin_amdgcn_mfma_f32_32x32x16_bf16(pf[tt][j], mk8(a0, a1), o0, 0, 0, 0);
        o1 = __builtin_amdgcn_mfma_f32_32x32x16_bf16(pf[tt][j], mk8(b0, b1), o1, 0, 0, 0);
      }
    __builtin_amdgcn_s_setprio(0);

    __syncthreads();
  }
#undef STAGE

  // ---- epilogue: broadcast row sums via wave-local LDS, normalize, store
  lb[w][lm] = lsum;
  asm volatile("s_waitcnt lgkmcnt(0)" ::: "memory");
  __builtin_amdgcn_sched_barrier(0);
  const int b = bh >> 4, h = bh & 15;
#pragma unroll
  for (int r = 0; r < 16; ++r) {
    int cr = (r & 3) + 8 * (r >> 2) + 4 * hi;
    float inv = 1.0f / lb[w][cr];
    size_t ro = ((size_t)(b * 2048 + q0 + cr)) * 1024 + h * 64;
    Ab[ro + lm]      = f2bf(o0[r] * inv);
    Ab[ro + 32 + lm] = f2bf(o1[r] * inv);
  }
}

// ---------- GEMM2: [4096 x 1024 x 1024] + bias, fp32 out ----------
__global__ __launch_bounds__(256) void k_gemm_out(
    const u16* __restrict__ Ab,   // [4096][1024] bf16
    const u16* __restrict__ Wot,  // [1024][1024] bf16 (Wo^T)
    const float* __restrict__ bias, float* __restrict__ out) {
  __shared__ __align__(16) u16 As[128][32];
  __shared__ __align__(16) u16 Bs[128][32];
  const int tid = threadIdx.x;
  const int w = tid >> 6, l = tid & 63;
  const int bm = blockIdx.x * 128;
  const int bn = blockIdx.y * 128;
  const int wm = (w >> 1) * 64, wn = (w & 1) * 64;
  const int lm = l & 15, lg = l >> 4;

  f32x4 acc[4][4];
#pragma unroll
  for (int i = 0; i < 4; ++i)
#pragma unroll
    for (int j = 0; j < 4; ++j) acc[i][j] = f32x4{0.f, 0.f, 0.f, 0.f};

  const int srow = w * 16 + (l >> 2);
  const int scol = (l & 3) * 8;
  for (int k0 = 0; k0 < 1024; k0 += 32) {
#pragma unroll
    for (int j = 0; j < 2; ++j) {
      gld16(Ab  + (size_t)(bm + j * 64 + srow) * 1024 + k0 + scol, &As[j * 64 + w * 16][0]);
      gld16(Wot + (size_t)(bn + j * 64 + srow) * 1024 + k0 + scol, &Bs[j * 64 + w * 16][0]);
    }
    __syncthreads();
    bf16x8 af[4], bfr[4];
#pragma unroll
    for (int mt = 0; mt < 4; ++mt)
      af[mt] = *reinterpret_cast<const bf16x8*>(&As[wm + mt * 16 + lm][lg * 8]);
#pragma unroll
    for (int nt = 0; nt < 4; ++nt)
      bfr[nt] = *reinterpret_cast<const bf16x8*>(&Bs[wn + nt * 16 + lm][lg * 8]);
#pragma unroll
    for (int mt = 0; mt < 4; ++mt)
#pragma unroll
      for (int nt = 0; nt < 4; ++nt)
        acc[mt][nt] = __builtin_amdgcn_mfma_f32_16x16x32_bf16(af[mt], bfr[nt], acc[mt][nt], 0, 0, 0);
    __syncthreads();
  }
#pragma unroll
  for (int nt = 0; nt < 4; ++nt) {
    int gc = bn + wn + nt * 16 + lm;
    float bv = bias[gc];
#pragma unroll
    for (int mt = 0; mt < 4; ++mt) {
#pragma unroll
      for (int r = 0; r < 4; ++r) {
        int gr = bm + wm + mt * 16 + lg * 4 + r;
        out[(size_t)gr * 1024 + gc] = acc[mt][nt][r] + bv;
      }
    }
  }
}

extern "C" void kernel_launch(void* const* d_in, const int* in_sizes, int n_in,
                              void* d_out, int out_size, void* d_ws, size_t ws_size,
                              hipStream_t stream) {
  const float* X  = (const float*)d_in[0];
  const float* wq = (const float*)d_in[1];
  const float* wk = (const float*)d_in[2];
  const float* wv = (const float*)d_in[3];
  const float* wo = (const float*)d_in[4];
  const float* bo = (const float*)d_in[5];
  float* out = (float*)d_out;

  char* ws = (char*)d_ws;
  // [0,8M) Xb | [8,14M) Wqkv | [14,16M) Wot | [16,24M) Qb | [24,32M) Kb
  // [32,40M) Vt | [40,48M) Ab   -> peak 48MB
  u16* Xb   = (u16*)(ws);
  u16* Wqkv = (u16*)(ws + (size_t)(8u  << 20));
  u16* Wot  = (u16*)(ws + (size_t)(14u << 20));
  u16* Qb   = (u16*)(ws + (size_t)(16u << 20));
  u16* Kb   = (u16*)(ws + (size_t)(24u << 20));
  u16* Vt   = (u16*)(ws + (size_t)(32u << 20));
  u16* Ab   = (u16*)(ws + (size_t)(40u << 20));

  k_prep<<<dim3(32, 32, 5), dim3(32, 8), 0, stream>>>(X, wq, wk, wv, wo, Xb, Wqkv, Wot);
  k_gemm_qkv<<<dim3(32, 24), 256, 0, stream>>>(Xb, Wqkv, Qb, Kb, Vt);
  k_attn<<<dim3(32, 16), 256, 0, stream>>>(Qb, Kb, Vt, Ab);
  k_gemm_out<<<dim3(32, 8), 256, 0, stream>>>(Ab, Wot, bo, out);
}

// Round 17
// 122.096 us; speedup vs baseline: 1.0382x; 1.0382x over previous
//
#include <hip/hip_runtime.h>
#include <cstdint>
#include <cstddef>

typedef unsigned short u16;
typedef unsigned int u32;
typedef __bf16 bf16x8 __attribute__((ext_vector_type(8)));
typedef float f32x4 __attribute__((ext_vector_type(4)));
typedef float f32x16 __attribute__((ext_vector_type(16)));
typedef u32 u32x2 __attribute__((ext_vector_type(2)));
typedef u32 u32x4 __attribute__((ext_vector_type(4)));

#define AS1 __attribute__((address_space(1)))
#define AS3 __attribute__((address_space(3)))

__device__ __forceinline__ void gld16(const u16* g, u16* l) {
  __builtin_amdgcn_global_load_lds((const AS1 void*)(const void*)g,
                                   (AS3 void*)(void*)l, 16, 0, 0);
}

__device__ __forceinline__ u16 f2bf(float f) {
  union { float f; unsigned u; } x; x.f = f;
  return (u16)((x.u + 0x7fffu + ((x.u >> 16) & 1u)) >> 16);
}

// single-instruction exp2 (avoids any OCML call expansion; inputs bounded ~|14|)
__device__ __forceinline__ float fexp2(float x) {
  float r; asm("v_exp_f32 %0, %1" : "=v"(r) : "v"(x)); return r;
}

__device__ __forceinline__ f32x16 zf16() {
  f32x16 v;
#pragma unroll
  for (int i = 0; i < 16; ++i) v[i] = 0.f;
  return v;
}

__device__ __forceinline__ bf16x8 mk8(u32x2 a, u32x2 b) {
  union { u32x4 u; bf16x8 v; } x;
  x.u[0] = a[0]; x.u[1] = a[1]; x.u[2] = b[0]; x.u[3] = b[1];
  return x.v;
}

// ---------- fused prep: z<4 transpose weights fp32->bf16; z==4 convert X ----------
__global__ void k_prep(const float* __restrict__ X,
                       const float* __restrict__ wq, const float* __restrict__ wk,
                       const float* __restrict__ wv, const float* __restrict__ wo,
                       u16* __restrict__ Xb, u16* __restrict__ Wqkv, u16* __restrict__ Wot) {
  const int z = blockIdx.z;
  if (z == 4) {
    int bid = blockIdx.y * 32 + blockIdx.x;
    int tid = threadIdx.y * 32 + threadIdx.x;
#pragma unroll
    for (int k = 0; k < 4; ++k) {
      int i = bid * 1024 + k * 256 + tid;
      float4 v = reinterpret_cast<const float4*>(X)[i];
      ushort4 o;
      o.x = f2bf(v.x); o.y = f2bf(v.y); o.z = f2bf(v.z); o.w = f2bf(v.w);
      reinterpret_cast<ushort4*>(Xb)[i] = o;
    }
    return;
  }
  __shared__ float t[32][33];
  const float* in = (z == 0) ? wq : (z == 1) ? wk : (z == 2) ? wv : wo;
  u16* out = (z < 3) ? (Wqkv + (size_t)z * 1048576) : Wot;
  int bx = blockIdx.x * 32, by = blockIdx.y * 32;
  int tx = threadIdx.x, ty = threadIdx.y;  // (32, 8)
#pragma unroll
  for (int j = 0; j < 32; j += 8)
    t[ty + j][tx] = in[(size_t)(by + ty + j) * 1024 + bx + tx];
  __syncthreads();
#pragma unroll
  for (int j = 0; j < 32; j += 8)
    out[(size_t)(bx + ty + j) * 1024 + by + tx] = f2bf(t[tx][ty + j]);
}

// ---------- GEMM1: [4096 x 3072 x 1024], epilogue scatters Q(scaled)/K/V^T ----------
// Q pre-scaled by DIM_HEAD^-0.5 * log2(e) so attention softmax runs in exp2 domain.
__global__ __launch_bounds__(256) void k_gemm_qkv(
    const u16* __restrict__ Xb,   // [4096][1024] bf16
    const u16* __restrict__ Wt,   // [3072][1024] bf16 (W^T, q|k|v stacked)
    u16* __restrict__ Qb,         // [B*H][2048][64], pre-scaled
    u16* __restrict__ Kb,         // [B*H][2048][64]
    u16* __restrict__ Vt) {       // [B*H][64][2048]
  __shared__ __align__(16) u16 As[128][32];
  __shared__ __align__(16) u16 Bs[128][32];
  const int tid = threadIdx.x;
  const int w = tid >> 6, l = tid & 63;
  const int bm = blockIdx.x * 128;
  const int bn = blockIdx.y * 128;
  const int wm = (w >> 1) * 64, wn = (w & 1) * 64;
  const int lm = l & 15, lg = l >> 4;

  f32x4 acc[4][4];
#pragma unroll
  for (int i = 0; i < 4; ++i)
#pragma unroll
    for (int j = 0; j < 4; ++j) acc[i][j] = f32x4{0.f, 0.f, 0.f, 0.f};

  const int srow = w * 16 + (l >> 2);   // 4 lanes/row, 16 rows per wave-issue
  const int scol = (l & 3) * 8;
  for (int k0 = 0; k0 < 1024; k0 += 32) {
#pragma unroll
    for (int j = 0; j < 2; ++j) {
      gld16(Xb + (size_t)(bm + j * 64 + srow) * 1024 + k0 + scol, &As[j * 64 + w * 16][0]);
      gld16(Wt + (size_t)(bn + j * 64 + srow) * 1024 + k0 + scol, &Bs[j * 64 + w * 16][0]);
    }
    __syncthreads();
    bf16x8 af[4], bfr[4];
#pragma unroll
    for (int mt = 0; mt < 4; ++mt)
      af[mt] = *reinterpret_cast<const bf16x8*>(&As[wm + mt * 16 + lm][lg * 8]);
#pragma unroll
    for (int nt = 0; nt < 4; ++nt)
      bfr[nt] = *reinterpret_cast<const bf16x8*>(&Bs[wn + nt * 16 + lm][lg * 8]);
#pragma unroll
    for (int mt = 0; mt < 4; ++mt)
#pragma unroll
      for (int nt = 0; nt < 4; ++nt)
        acc[mt][nt] = __builtin_amdgcn_mfma_f32_16x16x32_bf16(af[mt], bfr[nt], acc[mt][nt], 0, 0, 0);
    __syncthreads();
  }
  // epilogue: C/D layout col=lane&15, row=(lane>>4)*4+reg
#pragma unroll
  for (int nt = 0; nt < 4; ++nt) {
    int gc = bn + wn + nt * 16 + lm;
    int which = gc >> 10, jc = gc & 1023, h = jc >> 6, d = jc & 63;
#pragma unroll
    for (int mt = 0; mt < 4; ++mt) {
#pragma unroll
      for (int r = 0; r < 4; ++r) {
        int gr = bm + wm + mt * 16 + lg * 4 + r;
        int b = gr >> 11, s = gr & 2047;
        float v = acc[mt][nt][r];
        size_t bh = (size_t)(b * 16 + h);
        if (which == 0)      Qb[(bh * 2048 + s) * 64 + d] = f2bf(v * 0.18033688f);
        else if (which == 1) Kb[(bh * 2048 + s) * 64 + d] = f2bf(v);
        else                 Vt[(bh * 64 + d) * 2048 + s] = f2bf(v);
      }
    }
  }
}

// ---------- flash attention, swapped-QK^T 32x32, m=0 softmax ----------
// R11 structure (per-subtile QK^T+softmax, one f32x16 st live, 16 MFMA/tile,
// VALU row-sums, v_exp_f32, 80 VGPR) with the UNPADDED R8 LDS layout
// ([64][64] u16, 16B-granule XOR row&7) -- A/B test: padded layout had
// 10.5M bank conflicts vs 6.3M unpadded.
__global__ __launch_bounds__(256) void k_attn(
    const u16* __restrict__ Qb, const u16* __restrict__ Kb,
    const u16* __restrict__ Vt, u16* __restrict__ Ab) {  // Ab: [4096][1024] bf16
  __shared__ __align__(16) u16 Ks[2][64][64];   // [buf][kv][d], granule XOR row&7
  __shared__ __align__(16) u16 Vs[2][64][64];   // [buf][d][kv], granule XOR row&7
  __shared__ float lb[4][32];
  const int tid = threadIdx.x, w = tid >> 6, l = tid & 63;
  const int lm = l & 31, hi = l >> 5;
  const int kx = lm & 7;
  const int bh = blockIdx.x;
  const int q0 = blockIdx.y * 128 + w * 32;
  const u16* Qh = Qb + (size_t)bh * 2048 * 64;
  const u16* Kh = Kb + (size_t)bh * 2048 * 64;
  const u16* Vh = Vt + (size_t)bh * 64 * 2048;

  // Q fragments (held whole kernel): q = q0+lm, slot (c,hi,i) -> d = 16c+8hi+i
  bf16x8 qf[4];
#pragma unroll
  for (int c = 0; c < 4; ++c)
    qf[c] = *reinterpret_cast<const bf16x8*>(&Qh[(size_t)(q0 + lm) * 64 + 16 * c + 8 * hi]);

  f32x16 o0 = zf16(), o1 = zf16();
  float lsum = 0.f;

  const int sr8 = l >> 3;    // staging row within 8
  const int sg = l & 7;      // staging phys granule

#define STAGE(tile, buf)                                                        \
  {                                                                             \
    const int kvn_ = (tile) * 64;                                               \
    _Pragma("unroll")                                                           \
    for (int j = 0; j < 2; ++j) {                                               \
      int row_ = w * 16 + j * 8 + sr8;                                          \
      int g_ = sg ^ sr8;                                                        \
      gld16(Kh + (size_t)(kvn_ + row_) * 64 + 8 * g_, &Ks[buf][w * 16 + j * 8][0]); \
      gld16(Vh + (size_t)row_ * 2048 + kvn_ + 8 * g_, &Vs[buf][w * 16 + j * 8][0]); \
    }                                                                           \
  }

  // ---- prologue: stage tile 0 into buf 0
  STAGE(0, 0);
  __syncthreads();

  for (int t = 0; t < 32; ++t) {
    const int cur = t & 1, nxt = cur ^ 1;

    // ---- issue next tile's K,V DMA (completes at the end-of-tile barrier)
    if (t < 31) STAGE(t + 1, nxt);

    const u16* Kc = &Ks[cur][0][0];
    bf16x8 pf[2][2];
    float ps0 = 0.f, ps1 = 0.f, ps2 = 0.f, ps3 = 0.f;

    // ---- subtile 0: S^T rows lm (kv 0..31 of tile), then its softmax
    {
      f32x16 st = zf16();
      __builtin_amdgcn_s_setprio(1);
#pragma unroll
      for (int c = 0; c < 4; ++c) {
        bf16x8 kf = *reinterpret_cast<const bf16x8*>(Kc + (size_t)lm * 64 + 8 * ((2 * c + hi) ^ kx));
        st = __builtin_amdgcn_mfma_f32_32x32x16_bf16(kf, qf[c], st, 0, 0, 0);
      }
      __builtin_amdgcn_s_setprio(0);
#pragma unroll
      for (int j = 0; j < 2; ++j)
#pragma unroll
        for (int ii = 0; ii < 8; ++ii) {
          float p = fexp2(st[8 * j + ii]);
          pf[0][j][ii] = (__bf16)p;
          if ((ii & 3) == 0)      ps0 += p;
          else if ((ii & 3) == 1) ps1 += p;
          else if ((ii & 3) == 2) ps2 += p;
          else                    ps3 += p;
        }
    }
    // ---- subtile 1: S^T rows 32+lm (kv 32..63 of tile), then its softmax
    {
      f32x16 st = zf16();
      __builtin_amdgcn_s_setprio(1);
#pragma unroll
      for (int c = 0; c < 4; ++c) {
        bf16x8 kf = *reinterpret_cast<const bf16x8*>(Kc + (size_t)(32 + lm) * 64 + 8 * ((2 * c + hi) ^ kx));
        st = __builtin_amdgcn_mfma_f32_32x32x16_bf16(kf, qf[c], st, 0, 0, 0);
      }
      __builtin_amdgcn_s_setprio(0);
#pragma unroll
      for (int j = 0; j < 2; ++j)
#pragma unroll
        for (int ii = 0; ii < 8; ++ii) {
          float p = fexp2(st[8 * j + ii]);
          pf[1][j][ii] = (__bf16)p;
          if ((ii & 3) == 0)      ps0 += p;
          else if ((ii & 3) == 1) ps1 += p;
          else if ((ii & 3) == 2) ps2 += p;
          else                    ps3 += p;
        }
    }
    float ps = (ps0 + ps1) + (ps2 + ps3);
    ps += __shfl_xor(ps, 32);
    lsum += ps;

    // ---- O += P V
    const u16* Vc = &Vs[cur][0][0];
    __builtin_amdgcn_s_setprio(1);
#pragma unroll
    for (int tt = 0; tt < 2; ++tt)
#pragma unroll
      for (int j = 0; j < 2; ++j) {
        int Ga = 4 * tt + 2 * j;
        u32x2 a0 = *reinterpret_cast<const u32x2*>(Vc + (size_t)lm * 64 + 8 * (Ga ^ kx) + 4 * hi);
        u32x2 a1 = *reinterpret_cast<const u32x2*>(Vc + (size_t)lm * 64 + 8 * ((Ga + 1) ^ kx) + 4 * hi);
        u32x2 b0 = *reinterpret_cast<const u32x2*>(Vc + (size_t)(32 + lm) * 64 + 8 * (Ga ^ kx) + 4 * hi);
        u32x2 b1 = *reinterpret_cast<const u32x2*>(Vc + (size_t)(32 + lm) * 64 + 8 * ((Ga + 1) ^ kx) + 4 * hi);
        o0 = __builtin_amdgcn_mfma_f32_32x32x16_bf16(pf[tt][j], mk8(a0, a1), o0, 0, 0, 0);
        o1 = __builtin_amdgcn_mfma_f32_32x32x16_bf16(pf[tt][j], mk8(b0, b1), o1, 0, 0, 0);
      }
    __builtin_amdgcn_s_setprio(0);

    __syncthreads();
  }
#undef STAGE

  // ---- epilogue: broadcast row sums via wave-local LDS, normalize, store
  lb[w][lm] = lsum;
  asm volatile("s_waitcnt lgkmcnt(0)" ::: "memory");
  __builtin_amdgcn_sched_barrier(0);
  const int b = bh >> 4, h = bh & 15;
#pragma unroll
  for (int r = 0; r < 16; ++r) {
    int cr = (r & 3) + 8 * (r >> 2) + 4 * hi;
    float inv = 1.0f / lb[w][cr];
    size_t ro = ((size_t)(b * 2048 + q0 + cr)) * 1024 + h * 64;
    Ab[ro + lm]      = f2bf(o0[r] * inv);
    Ab[ro + 32 + lm] = f2bf(o1[r] * inv);
  }
}

// ---------- GEMM2: [4096 x 1024 x 1024] + bias, fp32 out ----------
__global__ __launch_bounds__(256) void k_gemm_out(
    const u16* __restrict__ Ab,   // [4096][1024] bf16
    const u16* __restrict__ Wot,  // [1024][1024] bf16 (Wo^T)
    const float* __restrict__ bias, float* __restrict__ out) {
  __shared__ __align__(16) u16 As[128][32];
  __shared__ __align__(16) u16 Bs[128][32];
  const int tid = threadIdx.x;
  const int w = tid >> 6, l = tid & 63;
  const int bm = blockIdx.x * 128;
  const int bn = blockIdx.y * 128;
  const int wm = (w >> 1) * 64, wn = (w & 1) * 64;
  const int lm = l & 15, lg = l >> 4;

  f32x4 acc[4][4];
#pragma unroll
  for (int i = 0; i < 4; ++i)
#pragma unroll
    for (int j = 0; j < 4; ++j) acc[i][j] = f32x4{0.f, 0.f, 0.f, 0.f};

  const int srow = w * 16 + (l >> 2);
  const int scol = (l & 3) * 8;
  for (int k0 = 0; k0 < 1024; k0 += 32) {
#pragma unroll
    for (int j = 0; j < 2; ++j) {
      gld16(Ab  + (size_t)(bm + j * 64 + srow) * 1024 + k0 + scol, &As[j * 64 + w * 16][0]);
      gld16(Wot + (size_t)(bn + j * 64 + srow) * 1024 + k0 + scol, &Bs[j * 64 + w * 16][0]);
    }
    __syncthreads();
    bf16x8 af[4], bfr[4];
#pragma unroll
    for (int mt = 0; mt < 4; ++mt)
      af[mt] = *reinterpret_cast<const bf16x8*>(&As[wm + mt * 16 + lm][lg * 8]);
#pragma unroll
    for (int nt = 0; nt < 4; ++nt)
      bfr[nt] = *reinterpret_cast<const bf16x8*>(&Bs[wn + nt * 16 + lm][lg * 8]);
#pragma unroll
    for (int mt = 0; mt < 4; ++mt)
#pragma unroll
      for (int nt = 0; nt < 4; ++nt)
        acc[mt][nt] = __builtin_amdgcn_mfma_f32_16x16x32_bf16(af[mt], bfr[nt], acc[mt][nt], 0, 0, 0);
    __syncthreads();
  }
#pragma unroll
  for (int nt = 0; nt < 4; ++nt) {
    int gc = bn + wn + nt * 16 + lm;
    float bv = bias[gc];
#pragma unroll
    for (int mt = 0; mt < 4; ++mt) {
#pragma unroll
      for (int r = 0; r < 4; ++r) {
        int gr = bm + wm + mt * 16 + lg * 4 + r;
        out[(size_t)gr * 1024 + gc] = acc[mt][nt][r] + bv;
      }
    }
  }
}

extern "C" void kernel_launch(void* const* d_in, const int* in_sizes, int n_in,
                              void* d_out, int out_size, void* d_ws, size_t ws_size,
                              hipStream_t stream) {
  const float* X  = (const float*)d_in[0];
  const float* wq = (const float*)d_in[1];
  const float* wk = (const float*)d_in[2];
  const float* wv = (const float*)d_in[3];
  const float* wo = (const float*)d_in[4];
  const float* bo = (const float*)d_in[5];
  float* out = (float*)d_out;

  char* ws = (char*)d_ws;
  // [0,8M) Xb | [8,14M) Wqkv | [14,16M) Wot | [16,24M) Qb | [24,32M) Kb
  // [32,40M) Vt | [40,48M) Ab   -> peak 48MB
  u16* Xb   = (u16*)(ws);
  u16* Wqkv = (u16*)(ws + (size_t)(8u  << 20));
  u16* Wot  = (u16*)(ws + (size_t)(14u << 20));
  u16* Qb   = (u16*)(ws + (size_t)(16u << 20));
  u16* Kb   = (u16*)(ws + (size_t)(24u << 20));
  u16* Vt   = (u16*)(ws + (size_t)(32u << 20));
  u16* Ab   = (u16*)(ws + (size_t)(40u << 20));

  k_prep<<<dim3(32, 32, 5), dim3(32, 8), 0, stream>>>(X, wq, wk, wv, wo, Xb, Wqkv, Wot);
  k_gemm_qkv<<<dim3(32, 24), 256, 0, stream>>>(Xb, Wqkv, Qb, Kb, Vt);
  k_attn<<<dim3(32, 16), 256, 0, stream>>>(Qb, Kb, Vt, Ab);
  k_gemm_out<<<dim3(32, 8), 256, 0, stream>>>(Ab, Wot, bo, out);
}

// Round 19
// 121.339 us; speedup vs baseline: 1.0447x; 1.0062x over previous
//
#include <hip/hip_runtime.h>
#include <cstdint>
#include <cstddef>

typedef unsigned short u16;
typedef unsigned int u32;
typedef __bf16 bf16x8 __attribute__((ext_vector_type(8)));
typedef float f32x4 __attribute__((ext_vector_type(4)));
typedef float f32x16 __attribute__((ext_vector_type(16)));
typedef u32 u32x2 __attribute__((ext_vector_type(2)));
typedef u32 u32x4 __attribute__((ext_vector_type(4)));

#define AS1 __attribute__((address_space(1)))
#define AS3 __attribute__((address_space(3)))

__device__ __forceinline__ void gld16(const u16* g, u16* l) {
  __builtin_amdgcn_global_load_lds((const AS1 void*)(const void*)g,
                                   (AS3 void*)(void*)l, 16, 0, 0);
}

__device__ __forceinline__ u16 f2bf(float f) {
  union { float f; unsigned u; } x; x.f = f;
  return (u16)((x.u + 0x7fffu + ((x.u >> 16) & 1u)) >> 16);
}

// single-instruction exp2 (avoids any OCML call expansion; inputs bounded ~|14|)
__device__ __forceinline__ float fexp2(float x) {
  float r; asm("v_exp_f32 %0, %1" : "=v"(r) : "v"(x)); return r;
}

__device__ __forceinline__ f32x16 zf16() {
  f32x16 v;
#pragma unroll
  for (int i = 0; i < 16; ++i) v[i] = 0.f;
  return v;
}

__device__ __forceinline__ bf16x8 mk8(u32x2 a, u32x2 b) {
  union { u32x4 u; bf16x8 v; } x;
  x.u[0] = a[0]; x.u[1] = a[1]; x.u[2] = b[0]; x.u[3] = b[1];
  return x.v;
}

// ---------- fused prep: z<4 transpose weights fp32->bf16; z==4 convert X ----------
__global__ void k_prep(const float* __restrict__ X,
                       const float* __restrict__ wq, const float* __restrict__ wk,
                       const float* __restrict__ wv, const float* __restrict__ wo,
                       u16* __restrict__ Xb, u16* __restrict__ Wqkv, u16* __restrict__ Wot) {
  const int z = blockIdx.z;
  if (z == 4) {
    int bid = blockIdx.y * 32 + blockIdx.x;
    int tid = threadIdx.y * 32 + threadIdx.x;
#pragma unroll
    for (int k = 0; k < 4; ++k) {
      int i = bid * 1024 + k * 256 + tid;
      float4 v = reinterpret_cast<const float4*>(X)[i];
      ushort4 o;
      o.x = f2bf(v.x); o.y = f2bf(v.y); o.z = f2bf(v.z); o.w = f2bf(v.w);
      reinterpret_cast<ushort4*>(Xb)[i] = o;
    }
    return;
  }
  __shared__ float t[32][33];
  const float* in = (z == 0) ? wq : (z == 1) ? wk : (z == 2) ? wv : wo;
  u16* out = (z < 3) ? (Wqkv + (size_t)z * 1048576) : Wot;
  int bx = blockIdx.x * 32, by = blockIdx.y * 32;
  int tx = threadIdx.x, ty = threadIdx.y;  // (32, 8)
#pragma unroll
  for (int j = 0; j < 32; j += 8)
    t[ty + j][tx] = in[(size_t)(by + ty + j) * 1024 + bx + tx];
  __syncthreads();
#pragma unroll
  for (int j = 0; j < 32; j += 8)
    out[(size_t)(bx + ty + j) * 1024 + by + tx] = f2bf(t[tx][ty + j]);
}

// ---------- GEMM1: [4096 x 3072 x 1024], epilogue scatters Q(scaled)/K/V^T ----------
// Q pre-scaled by DIM_HEAD^-0.5 * log2(e) so attention softmax runs in exp2 domain.
__global__ __launch_bounds__(256) void k_gemm_qkv(
    const u16* __restrict__ Xb,   // [4096][1024] bf16
    const u16* __restrict__ Wt,   // [3072][1024] bf16 (W^T, q|k|v stacked)
    u16* __restrict__ Qb,         // [B*H][2048][64], pre-scaled
    u16* __restrict__ Kb,         // [B*H][2048][64]
    u16* __restrict__ Vt) {       // [B*H][64][2048]
  __shared__ __align__(16) u16 As[128][32];
  __shared__ __align__(16) u16 Bs[128][32];
  const int tid = threadIdx.x;
  const int w = tid >> 6, l = tid & 63;
  const int bm = blockIdx.x * 128;
  const int bn = blockIdx.y * 128;
  const int wm = (w >> 1) * 64, wn = (w & 1) * 64;
  const int lm = l & 15, lg = l >> 4;

  f32x4 acc[4][4];
#pragma unroll
  for (int i = 0; i < 4; ++i)
#pragma unroll
    for (int j = 0; j < 4; ++j) acc[i][j] = f32x4{0.f, 0.f, 0.f, 0.f};

  const int srow = w * 16 + (l >> 2);   // 4 lanes/row, 16 rows per wave-issue
  const int scol = (l & 3) * 8;
  for (int k0 = 0; k0 < 1024; k0 += 32) {
#pragma unroll
    for (int j = 0; j < 2; ++j) {
      gld16(Xb + (size_t)(bm + j * 64 + srow) * 1024 + k0 + scol, &As[j * 64 + w * 16][0]);
      gld16(Wt + (size_t)(bn + j * 64 + srow) * 1024 + k0 + scol, &Bs[j * 64 + w * 16][0]);
    }
    __syncthreads();
    bf16x8 af[4], bfr[4];
#pragma unroll
    for (int mt = 0; mt < 4; ++mt)
      af[mt] = *reinterpret_cast<const bf16x8*>(&As[wm + mt * 16 + lm][lg * 8]);
#pragma unroll
    for (int nt = 0; nt < 4; ++nt)
      bfr[nt] = *reinterpret_cast<const bf16x8*>(&Bs[wn + nt * 16 + lm][lg * 8]);
#pragma unroll
    for (int mt = 0; mt < 4; ++mt)
#pragma unroll
      for (int nt = 0; nt < 4; ++nt)
        acc[mt][nt] = __builtin_amdgcn_mfma_f32_16x16x32_bf16(af[mt], bfr[nt], acc[mt][nt], 0, 0, 0);
    __syncthreads();
  }
  // epilogue: C/D layout col=lane&15, row=(lane>>4)*4+reg
#pragma unroll
  for (int nt = 0; nt < 4; ++nt) {
    int gc = bn + wn + nt * 16 + lm;
    int which = gc >> 10, jc = gc & 1023, h = jc >> 6, d = jc & 63;
#pragma unroll
    for (int mt = 0; mt < 4; ++mt) {
#pragma unroll
      for (int r = 0; r < 4; ++r) {
        int gr = bm + wm + mt * 16 + lg * 4 + r;
        int b = gr >> 11, s = gr & 2047;
        float v = acc[mt][nt][r];
        size_t bh = (size_t)(b * 16 + h);
        if (which == 0)      Qb[(bh * 2048 + s) * 64 + d] = f2bf(v * 0.18033688f);
        else if (which == 1) Kb[(bh * 2048 + s) * 64 + d] = f2bf(v);
        else                 Vt[(bh * 64 + d) * 2048 + s] = f2bf(v);
      }
    }
  }
}

// ---------- flash attention, swapped-QK^T 32x32, m=0 softmax (R11 verified) ----------
// Per-subtile QK^T+softmax (one f32x16 st live), 16 MFMA/tile, VALU row-sums,
// padded LDS groups (1056B stride), v_exp_f32. 512 blocks, 80 VGPR.
__global__ __launch_bounds__(256) void k_attn(
    const u16* __restrict__ Qb, const u16* __restrict__ Kb,
    const u16* __restrict__ Vt, u16* __restrict__ Ab) {  // Ab: [4096][1024] bf16
  __shared__ __align__(16) u16 Ks[2][4224];   // 2 x 8448B padded K tiles
  __shared__ __align__(16) u16 Vs[2][4224];   // 2 x 8448B padded V tiles [d][kv]
  __shared__ float lb[4][32];
  const int tid = threadIdx.x, w = tid >> 6, l = tid & 63;
  const int lm = l & 31, hi = l >> 5;
  const int kx = lm & 7;
  const int bh = blockIdx.x;
  const int q0 = blockIdx.y * 128 + w * 32;
  const u16* Qh = Qb + (size_t)bh * 2048 * 64;
  const u16* Kh = Kb + (size_t)bh * 2048 * 64;
  const u16* Vh = Vt + (size_t)bh * 64 * 2048;

  // Q fragments (held whole kernel): q = q0+lm, slot (c,hi,i) -> d = 16c+8hi+i
  bf16x8 qf[4];
#pragma unroll
  for (int c = 0; c < 4; ++c)
    qf[c] = *reinterpret_cast<const bf16x8*>(&Qh[(size_t)(q0 + lm) * 64 + 16 * c + 8 * hi]);

  f32x16 o0 = zf16(), o1 = zf16();
  float lsum = 0.f;

  const int sr8 = l >> 3;    // staging row within its 8-row group
  const int sg = l & 7;      // staging phys granule
  // padded row offset for row lm (and +2112 for row 32+lm)
  const int koff = (lm >> 3) * 528 + (lm & 7) * 64;

#define STAGE(tile, buf)                                                          \
  {                                                                               \
    const int kvn_ = (tile) * 64;                                                 \
    _Pragma("unroll")                                                             \
    for (int j = 0; j < 2; ++j) {                                                 \
      int row_ = w * 16 + j * 8 + sr8;                                            \
      int g_ = sg ^ sr8;                                                          \
      gld16(Kh + (size_t)(kvn_ + row_) * 64 + 8 * g_, &Ks[buf][(w * 2 + j) * 528]); \
      gld16(Vh + (size_t)row_ * 2048 + kvn_ + 8 * g_, &Vs[buf][(w * 2 + j) * 528]); \
    }                                                                             \
  }

  // ---- prologue: stage tile 0 into buf 0
  STAGE(0, 0);
  __syncthreads();

  for (int t = 0; t < 32; ++t) {
    const int cur = t & 1, nxt = cur ^ 1;

    // ---- issue next tile's K,V DMA (completes at the end-of-tile barrier)
    if (t < 31) STAGE(t + 1, nxt);

    const u16* Kc = &Ks[cur][0];
    bf16x8 pf[2][2];
    float ps0 = 0.f, ps1 = 0.f, ps2 = 0.f, ps3 = 0.f;

    // ---- subtile 0: S^T rows lm (kv 0..31 of tile), then its softmax
    {
      f32x16 st = zf16();
      __builtin_amdgcn_s_setprio(1);
#pragma unroll
      for (int c = 0; c < 4; ++c) {
        bf16x8 kf = *reinterpret_cast<const bf16x8*>(Kc + koff + 8 * ((2 * c + hi) ^ kx));
        st = __builtin_amdgcn_mfma_f32_32x32x16_bf16(kf, qf[c], st, 0, 0, 0);
      }
      __builtin_amdgcn_s_setprio(0);
#pragma unroll
      for (int j = 0; j < 2; ++j)
#pragma unroll
        for (int ii = 0; ii < 8; ++ii) {
          float p = fexp2(st[8 * j + ii]);
          pf[0][j][ii] = (__bf16)p;
          if ((ii & 3) == 0)      ps0 += p;
          else if ((ii & 3) == 1) ps1 += p;
          else if ((ii & 3) == 2) ps2 += p;
          else                    ps3 += p;
        }
    }
    // ---- subtile 1: S^T rows 32+lm (kv 32..63 of tile), then its softmax
    {
      f32x16 st = zf16();
      __builtin_amdgcn_s_setprio(1);
#pragma unroll
      for (int c = 0; c < 4; ++c) {
        bf16x8 kf = *reinterpret_cast<const bf16x8*>(Kc + koff + 2112 + 8 * ((2 * c + hi) ^ kx));
        st = __builtin_amdgcn_mfma_f32_32x32x16_bf16(kf, qf[c], st, 0, 0, 0);
      }
      __builtin_amdgcn_s_setprio(0);
#pragma unroll
      for (int j = 0; j < 2; ++j)
#pragma unroll
        for (int ii = 0; ii < 8; ++ii) {
          float p = fexp2(st[8 * j + ii]);
          pf[1][j][ii] = (__bf16)p;
          if ((ii & 3) == 0)      ps0 += p;
          else if ((ii & 3) == 1) ps1 += p;
          else if ((ii & 3) == 2) ps2 += p;
          else                    ps3 += p;
        }
    }
    float ps = (ps0 + ps1) + (ps2 + ps3);
    ps += __shfl_xor(ps, 32);
    lsum += ps;

    // ---- O += P V
    const u16* Vc = &Vs[cur][0];
    __builtin_amdgcn_s_setprio(1);
#pragma unroll
    for (int tt = 0; tt < 2; ++tt)
#pragma unroll
      for (int j = 0; j < 2; ++j) {
        int Ga = 4 * tt + 2 * j;
        u32x2 a0 = *reinterpret_cast<const u32x2*>(Vc + koff + 8 * (Ga ^ kx) + 4 * hi);
        u32x2 a1 = *reinterpret_cast<const u32x2*>(Vc + koff + 8 * ((Ga + 1) ^ kx) + 4 * hi);
        u32x2 b0 = *reinterpret_cast<const u32x2*>(Vc + koff + 2112 + 8 * (Ga ^ kx) + 4 * hi);
        u32x2 b1 = *reinterpret_cast<const u32x2*>(Vc + koff + 2112 + 8 * ((Ga + 1) ^ kx) + 4 * hi);
        o0 = __builtin_amdgcn_mfma_f32_32x32x16_bf16(pf[tt][j], mk8(a0, a1), o0, 0, 0, 0);
        o1 = __builtin_amdgcn_mfma_f32_32x32x16_bf16(pf[tt][j], mk8(b0, b1), o1, 0, 0, 0);
      }
    __builtin_amdgcn_s_setprio(0);

    __syncthreads();
  }
#undef STAGE

  // ---- epilogue: broadcast row sums via wave-local LDS, normalize, store
  lb[w][lm] = lsum;
  asm volatile("s_waitcnt lgkmcnt(0)" ::: "memory");
  __builtin_amdgcn_sched_barrier(0);
  const int b = bh >> 4, h = bh & 15;
#pragma unroll
  for (int r = 0; r < 16; ++r) {
    int cr = (r & 3) + 8 * (r >> 2) + 4 * hi;
    float inv = 1.0f / lb[w][cr];
    size_t ro = ((size_t)(b * 2048 + q0 + cr)) * 1024 + h * 64;
    Ab[ro + lm]      = f2bf(o0[r] * inv);
    Ab[ro + 32 + lm] = f2bf(o1[r] * inv);
  }
}

// ---------- GEMM2: [4096 x 1024 x 1024] + bias, fp32 out ----------
__global__ __launch_bounds__(256) void k_gemm_out(
    const u16* __restrict__ Ab,   // [4096][1024] bf16
    const u16* __restrict__ Wot,  // [1024][1024] bf16 (Wo^T)
    const float* __restrict__ bias, float* __restrict__ out) {
  __shared__ __align__(16) u16 As[128][32];
  __shared__ __align__(16) u16 Bs[128][32];
  const int tid = threadIdx.x;
  const int w = tid >> 6, l = tid & 63;
  const int bm = blockIdx.x * 128;
  const int bn = blockIdx.y * 128;
  const int wm = (w >> 1) * 64, wn = (w & 1) * 64;
  const int lm = l & 15, lg = l >> 4;

  f32x4 acc[4][4];
#pragma unroll
  for (int i = 0; i < 4; ++i)
#pragma unroll
    for (int j = 0; j < 4; ++j) acc[i][j] = f32x4{0.f, 0.f, 0.f, 0.f};

  const int srow = w * 16 + (l >> 2);
  const int scol = (l & 3) * 8;
  for (int k0 = 0; k0 < 1024; k0 += 32) {
#pragma unroll
    for (int j = 0; j < 2; ++j) {
      gld16(Ab  + (size_t)(bm + j * 64 + srow) * 1024 + k0 + scol, &As[j * 64 + w * 16][0]);
      gld16(Wot + (size_t)(bn + j * 64 + srow) * 1024 + k0 + scol, &Bs[j * 64 + w * 16][0]);
    }
    __syncthreads();
    bf16x8 af[4], bfr[4];
#pragma unroll
    for (int mt = 0; mt < 4; ++mt)
      af[mt] = *reinterpret_cast<const bf16x8*>(&As[wm + mt * 16 + lm][lg * 8]);
#pragma unroll
    for (int nt = 0; nt < 4; ++nt)
      bfr[nt] = *reinterpret_cast<const bf16x8*>(&Bs[wn + nt * 16 + lm][lg * 8]);
#pragma unroll
    for (int mt = 0; mt < 4; ++mt)
#pragma unroll
      for (int nt = 0; nt < 4; ++nt)
        acc[mt][nt] = __builtin_amdgcn_mfma_f32_16x16x32_bf16(af[mt], bfr[nt], acc[mt][nt], 0, 0, 0);
    __syncthreads();
  }
#pragma unroll
  for (int nt = 0; nt < 4; ++nt) {
    int gc = bn + wn + nt * 16 + lm;
    float bv = bias[gc];
#pragma unroll
    for (int mt = 0; mt < 4; ++mt) {
#pragma unroll
      for (int r = 0; r < 4; ++r) {
        int gr = bm + wm + mt * 16 + lg * 4 + r;
        out[(size_t)gr * 1024 + gc] = acc[mt][nt][r] + bv;
      }
    }
  }
}

extern "C" void kernel_launch(void* const* d_in, const int* in_sizes, int n_in,
                              void* d_out, int out_size, void* d_ws, size_t ws_size,
                              hipStream_t stream) {
  const float* X  = (const float*)d_in[0];
  const float* wq = (const float*)d_in[1];
  const float* wk = (const float*)d_in[2];
  const float* wv = (const float*)d_in[3];
  const float* wo = (const float*)d_in[4];
  const float* bo = (const float*)d_in[5];
  float* out = (float*)d_out;

  char* ws = (char*)d_ws;
  // [0,8M) Xb | [8,14M) Wqkv | [14,16M) Wot | [16,24M) Qb | [24,32M) Kb
  // [32,40M) Vt | [40,48M) Ab   -> peak 48MB
  u16* Xb   = (u16*)(ws);
  u16* Wqkv = (u16*)(ws + (size_t)(8u  << 20));
  u16* Wot  = (u16*)(ws + (size_t)(14u << 20));
  u16* Qb   = (u16*)(ws + (size_t)(16u << 20));
  u16* Kb   = (u16*)(ws + (size_t)(24u << 20));
  u16* Vt   = (u16*)(ws + (size_t)(32u << 20));
  u16* Ab   = (u16*)(ws + (size_t)(40u << 20));

  k_prep<<<dim3(32, 32, 5), dim3(32, 8), 0, stream>>>(X, wq, wk, wv, wo, Xb, Wqkv, Wot);
  k_gemm_qkv<<<dim3(32, 24), 256, 0, stream>>>(Xb, Wqkv, Qb, Kb, Vt);
  k_attn<<<dim3(32, 16), 256, 0, stream>>>(Qb, Kb, Vt, Ab);
  k_gemm_out<<<dim3(32, 8), 256, 0, stream>>>(Ab, Wot, bo, out);
}